// Round 7
// baseline (246.986 us; speedup 1.0000x reference)
//
#include <hip/hip_runtime.h>
#include <hip/hip_bf16.h>
#include <cstdint>

#define N_TOK 4096
#define KTOP  64
#define DIM   1024
#define NLAT  16384
#define NCHUNK 8      // 128 cols/chunk -> 4 MB bf16 per chunk == one XCD L2

typedef __bf16 bf16x8 __attribute__((ext_vector_type(8)));
typedef float  floatx4 __attribute__((ext_vector_type(4)));
typedef float  f32x4   __attribute__((ext_vector_type(4)));
typedef unsigned int   u32x2   __attribute__((ext_vector_type(2)));
typedef unsigned short ushortx8 __attribute__((ext_vector_type(8)));

#define GLOBAL_AS(p) ((const __attribute__((address_space(1))) void*)(p))
#define LDS_AS(p)    ((__attribute__((address_space(3))) void*)(p))

__device__ inline unsigned short f2bf(float f){
  unsigned int u = __float_as_uint(f);
  unsigned int r = (u + 0x7fffu + ((u >> 16) & 1u)) >> 16;  // RNE
  return (unsigned short)r;
}
__device__ inline float bflo(unsigned int u){ return __uint_as_float(u << 16); }
__device__ inline float bfhi(unsigned int u){ return __uint_as_float(u & 0xffff0000u); }

// two adjacent float4 -> one 16-byte ushort8 bf16 store (full store width)
__device__ inline ushortx8 cvt8p(f32x4 a, f32x4 b){
  ushortx8 o;
  o[0] = f2bf(a[0]); o[1] = f2bf(a[1]); o[2] = f2bf(a[2]); o[3] = f2bf(a[3]);
  o[4] = f2bf(b[0]); o[5] = f2bf(b[1]); o[6] = f2bf(b[2]); o[7] = f2bf(b[3]);
  return o;
}

// Roles:
//   [0,128)      ystats: colsum + sum(y^2), 32 rows/block, 4-deep load groups
//   [128,384)    x->bf16      (256 blocks)
//   [384,448)    Wskip->bf16  (64 blocks)
//   [448,2496)   Wdec->chunked bf16 (2048 blocks, 8 rows each, FULL 1024 cols:
//                j=t&127 covers 128 ushort8-pairs -> chunks 0..7; round-6 bug was
//                j=t&63 -> only cols 0..511 / chunks 0..3 written)
//   [2496,2560)  act precompute
// Conversion roles: 8 nt-loads, sched_barrier(0), 4x 16-B ushort8 stores.
// sched_barrier pins the 8-deep load window open (round-5 lesson: VGPR=36 showed
// the compiler collapsed the batch to ~2 in-flight loads -> 1.7 TB/s latency-bound).
// accs zeroed by hipMemsetAsync BEFORE this kernel.
__global__ __launch_bounds__(256) void prep(
    const float* __restrict__ x, const float* __restrict__ Wsk,
    const float* __restrict__ Wd, const float* __restrict__ y,
    const float* __restrict__ la, const int* __restrict__ li,
    const float* __restrict__ pe, const float* __restrict__ pes,
    unsigned short* __restrict__ xb, unsigned short* __restrict__ wb,
    unsigned short* __restrict__ wdc,
    uint2* __restrict__ actbuf, float* __restrict__ accs){
  const int b = blockIdx.x;
  const int t = threadIdx.x;
  __shared__ float s_red[4];
  if (b < 128){
    const int r0 = b * 32;
    const float4* y4 = (const float4*)y;
    float4 cs = {0.f, 0.f, 0.f, 0.f};
    float sq = 0.f;
    #pragma unroll
    for (int g = 0; g < 8; g++){
      float4 v0 = y4[(size_t)(r0 + g*4 + 0) * 256 + t];
      float4 v1 = y4[(size_t)(r0 + g*4 + 1) * 256 + t];
      float4 v2 = y4[(size_t)(r0 + g*4 + 2) * 256 + t];
      float4 v3 = y4[(size_t)(r0 + g*4 + 3) * 256 + t];
      cs.x += v0.x + v1.x + v2.x + v3.x;
      cs.y += v0.y + v1.y + v2.y + v3.y;
      cs.z += v0.z + v1.z + v2.z + v3.z;
      cs.w += v0.w + v1.w + v2.w + v3.w;
      sq += v0.x*v0.x + v0.y*v0.y + v0.z*v0.z + v0.w*v0.w;
      sq += v1.x*v1.x + v1.y*v1.y + v1.z*v1.z + v1.w*v1.w;
      sq += v2.x*v2.x + v2.y*v2.y + v2.z*v2.z + v2.w*v2.w;
      sq += v3.x*v3.x + v3.y*v3.y + v3.z*v3.z + v3.w*v3.w;
    }
    atomicAdd(&accs[4 + t*4 + 0], cs.x);
    atomicAdd(&accs[4 + t*4 + 1], cs.y);
    atomicAdd(&accs[4 + t*4 + 2], cs.z);
    atomicAdd(&accs[4 + t*4 + 3], cs.w);
    #pragma unroll
    for (int off = 32; off > 0; off >>= 1) sq += __shfl_down(sq, off, 64);
    if ((t & 63) == 0) s_red[t >> 6] = sq;
    __syncthreads();
    if (t == 0) atomicAdd(&accs[1], s_red[0] + s_red[1] + s_red[2] + s_red[3]);
  } else if (b < 384){
    const f32x4* xs = (const f32x4*)x;
    ushortx8* xd = (ushortx8*)xb;
    const int base = (b - 128) * 4096;          // float4 units
    #pragma unroll
    for (int u = 0; u < 2; u++){
      const int s0 = base + u * 2048;
      f32x4 va[4], vb[4];
      #pragma unroll
      for (int i = 0; i < 4; i++){
        va[i] = __builtin_nontemporal_load(xs + s0 + i*512 + 2*t);
        vb[i] = __builtin_nontemporal_load(xs + s0 + i*512 + 2*t + 1);
      }
      __builtin_amdgcn_sched_barrier(0);
      #pragma unroll
      for (int i = 0; i < 4; i++)
        xd[(s0 >> 1) + i*256 + t] = cvt8p(va[i], vb[i]);
      __builtin_amdgcn_sched_barrier(0);
    }
  } else if (b < 448){
    const f32x4* ws = (const f32x4*)Wsk;
    ushortx8* wd2 = (ushortx8*)wb;
    const int base = (b - 384) * 4096;
    #pragma unroll
    for (int u = 0; u < 2; u++){
      const int s0 = base + u * 2048;
      f32x4 va[4], vb[4];
      #pragma unroll
      for (int i = 0; i < 4; i++){
        va[i] = __builtin_nontemporal_load(ws + s0 + i*512 + 2*t);
        vb[i] = __builtin_nontemporal_load(ws + s0 + i*512 + 2*t + 1);
      }
      __builtin_amdgcn_sched_barrier(0);
      #pragma unroll
      for (int i = 0; i < 4; i++)
        wd2[(s0 >> 1) + i*256 + t] = cvt8p(va[i], vb[i]);
      __builtin_amdgcn_sched_barrier(0);
    }
  } else if (b < 2496){
    const f32x4* wsrc = (const f32x4*)Wd;
    ushortx8* wdst = (ushortx8*)wdc;
    const int r0 = (b - 448) * 8;
    const int lr = t >> 7;         // 0..1 (row within 2-row step)
    const int j  = t & 127;        // pair index: cols j*8 .. j*8+7 (FULL row)
    const int chunk = j >> 4;      // 0..7
    const int co    = j & 15;
    f32x4 va[4], vb[4];
    #pragma unroll
    for (int s = 0; s < 4; s++){
      const size_t row = r0 + s*2 + lr;
      va[s] = __builtin_nontemporal_load(wsrc + row*256 + 2*j);
      vb[s] = __builtin_nontemporal_load(wsrc + row*256 + 2*j + 1);
    }
    __builtin_amdgcn_sched_barrier(0);
    #pragma unroll
    for (int s = 0; s < 4; s++){
      const size_t row = r0 + s*2 + lr;
      wdst[((size_t)chunk * NLAT + row) * 16 + co] = cvt8p(va[s], vb[s]);
    }
  } else {
    int e0 = (b - 2496) * 4096 + t;
    #pragma unroll
    for (int i = 0; i < 16; i++){
      int e = e0 + i * 256;
      int id = li[e];
      float a = (la[e] + pe[id]) * pes[id];
      actbuf[e] = make_uint2(__float_as_uint(a), (unsigned)id * 256u);
    }
  }
}

// 128 rows x 64 cols tile -> 512 blocks (2 blocks/CU). m97-style staging. (unchanged)
__global__ __launch_bounds__(256) void skip_gemm(
    const unsigned short* __restrict__ xb,
    const unsigned short* __restrict__ wb,
    const float* __restrict__ b_dec,
    float* __restrict__ out){
  __shared__ unsigned short As[128][32];
  __shared__ unsigned short Bs[64][32];
  const int row0 = blockIdx.x * 128;
  const int col0 = blockIdx.y * 64;
  const int t    = threadIdx.x;
  const int lane = t & 63;
  const int w    = t >> 6;
  const int wr   = w * 32;
  const int lm   = lane & 15;
  const int kq   = lane >> 4;
  const int sr   = t >> 2;
  const int sc   = (t & 3) * 8;

  floatx4 acc[2][4] = {};

  for (int k0 = 0; k0 < DIM; k0 += 32){
    __builtin_amdgcn_global_load_lds(GLOBAL_AS(xb + (size_t)(row0 + sr) * DIM + k0 + sc),
                                     LDS_AS(&As[sr][sc]), 16, 0, 0);
    __builtin_amdgcn_global_load_lds(GLOBAL_AS(xb + (size_t)(row0 + 64 + sr) * DIM + k0 + sc),
                                     LDS_AS(&As[64 + sr][sc]), 16, 0, 0);
    __builtin_amdgcn_global_load_lds(GLOBAL_AS(wb + (size_t)(col0 + sr) * DIM + k0 + sc),
                                     LDS_AS(&Bs[sr][sc]), 16, 0, 0);
    __syncthreads();
    bf16x8 af[2], bfr[4];
    #pragma unroll
    for (int mi = 0; mi < 2; mi++) af[mi] = *(const bf16x8*)(&As[wr + mi * 16 + lm][kq * 8]);
    #pragma unroll
    for (int ni = 0; ni < 4; ni++) bfr[ni] = *(const bf16x8*)(&Bs[ni * 16 + lm][kq * 8]);
    #pragma unroll
    for (int mi = 0; mi < 2; mi++)
      #pragma unroll
      for (int ni = 0; ni < 4; ni++)
        acc[mi][ni] = __builtin_amdgcn_mfma_f32_16x16x32_bf16(af[mi], bfr[ni], acc[mi][ni], 0, 0, 0);
    __syncthreads();
  }

  const int rq = (lane >> 4) * 4;   // C/D: col=lane&15, row=(lane>>4)*4+reg
  #pragma unroll
  for (int mi = 0; mi < 2; mi++){
    #pragma unroll
    for (int ni = 0; ni < 4; ni++){
      int col = col0 + ni * 16 + lm;
      float bd = b_dec[col];
      #pragma unroll
      for (int r = 0; r < 4; r++){
        int row = row0 + wr + mi * 16 + rq + r;
        out[(size_t)row * DIM + col] = acc[mi][ni][r] + bd;
      }
    }
  }
}

// Chunked decode — round-0 structure (compiler-pipelined unroll-16 loop, minimal
// sse-only epilogue) + actbuf precompute + nt streams. No fences (buffer_inv wipes L2).
__global__ __launch_bounds__(256) void decode_residual(
    const float* __restrict__ y,
    const uint2* __restrict__ actbuf,
    const unsigned short* __restrict__ Wdc,  // [NCHUNK][NLAT][128] bf16
    float* __restrict__ out,
    float* __restrict__ sse){
  const int chunk = blockIdx.x & 7;          // == XCD id under round-robin dispatch
  const int tok0  = (blockIdx.x >> 3) * 16;
  const int t  = threadIdx.x;
  const int tl = t >> 4;       // token lane 0..15
  const int cl = t & 15;       // col lane (8 cols each)
  __shared__ uint2 s_ai[16][66];   // stride 66 -> conflict-free
  __shared__ float s_red[4];

  #pragma unroll
  for (int i = 0; i < 4; i++){
    int e = t + i * 256;                 // (tok = e>>6, k = e&63)
    u32x2 v = __builtin_nontemporal_load((const u32x2*)&actbuf[tok0 * KTOP + e]);
    s_ai[e >> 6][e & 63] = make_uint2(v[0], v[1]);
  }
  __syncthreads();
  const int n = tok0 + tl;
  const char* Wbase = (const char*)Wdc + (size_t)chunk * NLAT * 256 + cl * 16;
  float* op = out + (size_t)n * DIM + chunk * 128 + cl * 8;
  const float* yp = y + (size_t)n * DIM + chunk * 128 + cl * 8;
  f32x4 o0 = __builtin_nontemporal_load((const f32x4*)op);
  f32x4 o1 = __builtin_nontemporal_load((const f32x4*)op + 1);
  f32x4 y0 = __builtin_nontemporal_load((const f32x4*)yp);
  f32x4 y1 = __builtin_nontemporal_load((const f32x4*)yp + 1);

  float acc[8] = {};
  #pragma unroll 16
  for (int k = 0; k < KTOP; k++){
    uint2 p = s_ai[tl][k];
    const float a = __uint_as_float(p.x);
    const uint4 wv = *(const uint4*)(Wbase + p.y);
    acc[0] += a * bflo(wv.x); acc[1] += a * bfhi(wv.x);
    acc[2] += a * bflo(wv.y); acc[3] += a * bfhi(wv.y);
    acc[4] += a * bflo(wv.z); acc[5] += a * bfhi(wv.z);
    acc[6] += a * bflo(wv.w); acc[7] += a * bfhi(wv.w);
  }
  acc[0] += o0[0]; acc[1] += o0[1]; acc[2] += o0[2]; acc[3] += o0[3];
  acc[4] += o1[0]; acc[5] += o1[1]; acc[6] += o1[2]; acc[7] += o1[3];
  f32x4 r0 = {acc[0], acc[1], acc[2], acc[3]};
  f32x4 r1 = {acc[4], acc[5], acc[6], acc[7]};
  __builtin_nontemporal_store(r0, (f32x4*)op);
  __builtin_nontemporal_store(r1, (f32x4*)op + 1);

  float e0 = y0[0]-acc[0], e1 = y0[1]-acc[1], e2 = y0[2]-acc[2], e3 = y0[3]-acc[3];
  float e4 = y1[0]-acc[4], e5 = y1[1]-acc[5], e6 = y1[2]-acc[6], e7 = y1[3]-acc[7];
  float s = e0*e0 + e1*e1 + e2*e2 + e3*e3 + e4*e4 + e5*e5 + e6*e6 + e7*e7;
  #pragma unroll
  for (int off = 32; off > 0; off >>= 1) s += __shfl_down(s, off, 64);
  if ((t & 63) == 0) s_red[t >> 6] = s;
  __syncthreads();
  if (t == 0) atomicAdd(sse, s_red[0] + s_red[1] + s_red[2] + s_red[3]);
}

// Tiny finalize: fvu = sse / (sumsq - sum(colsum^2)/N). Kernel boundary gives visibility.
__global__ __launch_bounds__(256) void fvu_kernel(
    const float* __restrict__ ws, float* __restrict__ fvu_out){
  const int t = threadIdx.x;
  float4 c = ((const float4*)(ws + 4))[t];
  float s = c.x*c.x + c.y*c.y + c.z*c.z + c.w*c.w;
  #pragma unroll
  for (int off = 32; off > 0; off >>= 1) s += __shfl_down(s, off, 64);
  __shared__ float s_red[4];
  if ((t & 63) == 0) s_red[t >> 6] = s;
  __syncthreads();
  if (t == 0){
    float ss = s_red[0] + s_red[1] + s_red[2] + s_red[3];
    float tv = ws[1] - ss / (float)N_TOK;
    fvu_out[0] = ws[0] / tv;
  }
}

extern "C" void kernel_launch(void* const* d_in, const int* in_sizes, int n_in,
                              void* d_out, int out_size, void* d_ws, size_t ws_size,
                              hipStream_t stream){
  const float* x   = (const float*)d_in[0];
  const float* y   = (const float*)d_in[1];
  const float* la  = (const float*)d_in[2];
  const int*   li  = (const int*)d_in[3];
  const float* Wd  = (const float*)d_in[4];
  const float* bd  = (const float*)d_in[5];
  const float* pe  = (const float*)d_in[6];
  const float* pes = (const float*)d_in[7];
  const float* Wsk = (const float*)d_in[8];
  float* out = (float*)d_out;

  float* accs = (float*)d_ws;  // [0]=sse [1]=sumsq [4..1028)=colsum
  unsigned short* xb  = (unsigned short*)((char*)d_ws + 8192);
  unsigned short* wb  = xb + (size_t)N_TOK * DIM;
  unsigned short* wdc = wb + (size_t)DIM * DIM;
  uint2* actbuf = (uint2*)(wdc + (size_t)NCHUNK * NLAT * 128);

  hipMemsetAsync(d_ws, 0, 8192, stream);
  prep<<<2560, 256, 0, stream>>>(x, Wsk, Wd, y, la, li, pe, pes, xb, wb, wdc, actbuf, accs);
  skip_gemm<<<dim3(N_TOK / 128, DIM / 64), 256, 0, stream>>>(xb, wb, bd, out);
  decode_residual<<<(N_TOK / 16) * NCHUNK, 256, 0, stream>>>(y, actbuf, wdc, out, accs);
  fvu_kernel<<<1, 256, 0, stream>>>(accs, out + (size_t)N_TOK * DIM);
}

// Round 8
// 242.221 us; speedup vs baseline: 1.0197x; 1.0197x over previous
//
#include <hip/hip_runtime.h>
#include <hip/hip_bf16.h>
#include <cstdint>

#define N_TOK 4096
#define KTOP  64
#define DIM   1024
#define NLAT  16384
#define NCHUNK 8      // 128-col stripe/chunk -> 4 MB bf16 working set == one XCD L2

typedef __bf16 bf16x8 __attribute__((ext_vector_type(8)));
typedef float  floatx4 __attribute__((ext_vector_type(4)));
typedef float  f32x4   __attribute__((ext_vector_type(4)));
typedef unsigned int   u32x2   __attribute__((ext_vector_type(2)));
typedef unsigned short ushortx8 __attribute__((ext_vector_type(8)));

#define GLOBAL_AS(p) ((const __attribute__((address_space(1))) void*)(p))
#define LDS_AS(p)    ((__attribute__((address_space(3))) void*)(p))

__device__ inline unsigned short f2bf(float f){
  unsigned int u = __float_as_uint(f);
  unsigned int r = (u + 0x7fffu + ((u >> 16) & 1u)) >> 16;  // RNE
  return (unsigned short)r;
}
__device__ inline float bflo(unsigned int u){ return __uint_as_float(u << 16); }
__device__ inline float bfhi(unsigned int u){ return __uint_as_float(u & 0xffff0000u); }

// two adjacent float4 -> one 16-byte ushort8 bf16 store (full store width)
__device__ inline ushortx8 cvt8p(f32x4 a, f32x4 b){
  ushortx8 o;
  o[0] = f2bf(a[0]); o[1] = f2bf(a[1]); o[2] = f2bf(a[2]); o[3] = f2bf(a[3]);
  o[4] = f2bf(b[0]); o[5] = f2bf(b[1]); o[6] = f2bf(b[2]); o[7] = f2bf(b[3]);
  return o;
}

// Unified row converter: 8 rows of [*, 1024] f32 -> bf16, SAME layout (linear).
// 8 nt-loads batched, sched_barrier, 4x 16-B fully-coalesced stores (1 KB/wave).
__device__ inline void cvt_rows8(const f32x4* __restrict__ src, ushortx8* __restrict__ dst,
                                 int r0, int t){
  const int co = t & 127;      // ushort8 slot within row (128 slots = 1024 cols)
  const int lr = t >> 7;       // 0..1
  f32x4 va[4], vb[4];
  #pragma unroll
  for (int s = 0; s < 4; s++){
    const size_t row = r0 + s*2 + lr;
    va[s] = __builtin_nontemporal_load(src + row*256 + 2*co);
    vb[s] = __builtin_nontemporal_load(src + row*256 + 2*co + 1);
  }
  __builtin_amdgcn_sched_barrier(0);
  #pragma unroll
  for (int s = 0; s < 4; s++){
    const size_t row = r0 + s*2 + lr;
    dst[row*128 + co] = cvt8p(va[s], vb[s]);
  }
}

// Roles: [0,512) x | [512,640) Wskip | [640,2688) Wdec (linear!) | [2688,2752) acts
//        | 2752 zero accs. ystats moved into skip_gemm (overlaps MFMA); memset
//        dispatch eliminated (zero-role; prep has no atomics so no ordering race).
__global__ __launch_bounds__(256) void prep(
    const float* __restrict__ x, const float* __restrict__ Wsk,
    const float* __restrict__ Wd,
    const float* __restrict__ la, const int* __restrict__ li,
    const float* __restrict__ pe, const float* __restrict__ pes,
    unsigned short* __restrict__ xb, unsigned short* __restrict__ wb,
    unsigned short* __restrict__ wdb,
    uint2* __restrict__ actbuf, float* __restrict__ accs){
  const int b = blockIdx.x;
  const int t = threadIdx.x;
  if (b < 512){
    cvt_rows8((const f32x4*)x, (ushortx8*)xb, b * 8, t);
  } else if (b < 640){
    cvt_rows8((const f32x4*)Wsk, (ushortx8*)wb, (b - 512) * 8, t);
  } else if (b < 2688){
    cvt_rows8((const f32x4*)Wd, (ushortx8*)wdb, (b - 640) * 8, t);
  } else if (b < 2752){
    int e0 = (b - 2688) * 4096 + t;
    #pragma unroll
    for (int i = 0; i < 16; i++){
      int e = e0 + i * 256;
      int id = li[e];
      float a = (la[e] + pe[id]) * pes[id];
      actbuf[e] = make_uint2(__float_as_uint(a), (unsigned)id * 2048u);  // row byte off
    }
  } else {
    for (int i = t; i < 1056; i += 256) accs[i] = 0.f;  // sse, sumsq, colsum
  }
}

// GEMM (blockIdx.x<32, unchanged m97-style) + ystats role blocks (x>=32):
// 128 ystats blocks stream y (16.8 MB HBM) while MFMA blocks run on L2-resident
// panels -> overlap. accs pre-zeroed by prep.
__global__ __launch_bounds__(256) void skip_gemm(
    const unsigned short* __restrict__ xb,
    const unsigned short* __restrict__ wb,
    const float* __restrict__ b_dec,
    const float* __restrict__ y,
    float* __restrict__ out,
    float* __restrict__ accs){
  const int t = threadIdx.x;
  if (blockIdx.x >= 32){
    __shared__ float s_red[4];
    const int yb = (blockIdx.x - 32) * 16 + blockIdx.y;   // 0..127
    const int r0 = yb * 32;
    const float4* y4 = (const float4*)y;
    float4 cs = {0.f, 0.f, 0.f, 0.f};
    float sq = 0.f;
    #pragma unroll
    for (int g = 0; g < 8; g++){
      float4 v0 = y4[(size_t)(r0 + g*4 + 0) * 256 + t];
      float4 v1 = y4[(size_t)(r0 + g*4 + 1) * 256 + t];
      float4 v2 = y4[(size_t)(r0 + g*4 + 2) * 256 + t];
      float4 v3 = y4[(size_t)(r0 + g*4 + 3) * 256 + t];
      cs.x += v0.x + v1.x + v2.x + v3.x;
      cs.y += v0.y + v1.y + v2.y + v3.y;
      cs.z += v0.z + v1.z + v2.z + v3.z;
      cs.w += v0.w + v1.w + v2.w + v3.w;
      sq += v0.x*v0.x + v0.y*v0.y + v0.z*v0.z + v0.w*v0.w;
      sq += v1.x*v1.x + v1.y*v1.y + v1.z*v1.z + v1.w*v1.w;
      sq += v2.x*v2.x + v2.y*v2.y + v2.z*v2.z + v2.w*v2.w;
      sq += v3.x*v3.x + v3.y*v3.y + v3.z*v3.z + v3.w*v3.w;
    }
    atomicAdd(&accs[4 + t*4 + 0], cs.x);
    atomicAdd(&accs[4 + t*4 + 1], cs.y);
    atomicAdd(&accs[4 + t*4 + 2], cs.z);
    atomicAdd(&accs[4 + t*4 + 3], cs.w);
    #pragma unroll
    for (int off = 32; off > 0; off >>= 1) sq += __shfl_down(sq, off, 64);
    if ((t & 63) == 0) s_red[t >> 6] = sq;
    __syncthreads();
    if (t == 0) atomicAdd(&accs[1], s_red[0] + s_red[1] + s_red[2] + s_red[3]);
    return;
  }
  __shared__ unsigned short As[128][32];
  __shared__ unsigned short Bs[64][32];
  const int row0 = blockIdx.x * 128;
  const int col0 = blockIdx.y * 64;
  const int lane = t & 63;
  const int w    = t >> 6;
  const int wr   = w * 32;
  const int lm   = lane & 15;
  const int kq   = lane >> 4;
  const int sr   = t >> 2;
  const int sc   = (t & 3) * 8;

  floatx4 acc[2][4] = {};

  for (int k0 = 0; k0 < DIM; k0 += 32){
    __builtin_amdgcn_global_load_lds(GLOBAL_AS(xb + (size_t)(row0 + sr) * DIM + k0 + sc),
                                     LDS_AS(&As[sr][sc]), 16, 0, 0);
    __builtin_amdgcn_global_load_lds(GLOBAL_AS(xb + (size_t)(row0 + 64 + sr) * DIM + k0 + sc),
                                     LDS_AS(&As[64 + sr][sc]), 16, 0, 0);
    __builtin_amdgcn_global_load_lds(GLOBAL_AS(wb + (size_t)(col0 + sr) * DIM + k0 + sc),
                                     LDS_AS(&Bs[sr][sc]), 16, 0, 0);
    __syncthreads();
    bf16x8 af[2], bfr[4];
    #pragma unroll
    for (int mi = 0; mi < 2; mi++) af[mi] = *(const bf16x8*)(&As[wr + mi * 16 + lm][kq * 8]);
    #pragma unroll
    for (int ni = 0; ni < 4; ni++) bfr[ni] = *(const bf16x8*)(&Bs[ni * 16 + lm][kq * 8]);
    #pragma unroll
    for (int mi = 0; mi < 2; mi++)
      #pragma unroll
      for (int ni = 0; ni < 4; ni++)
        acc[mi][ni] = __builtin_amdgcn_mfma_f32_16x16x32_bf16(af[mi], bfr[ni], acc[mi][ni], 0, 0, 0);
    __syncthreads();
  }

  const int rq = (lane >> 4) * 4;   // C/D: col=lane&15, row=(lane>>4)*4+reg
  #pragma unroll
  for (int mi = 0; mi < 2; mi++){
    #pragma unroll
    for (int ni = 0; ni < 4; ni++){
      int col = col0 + ni * 16 + lm;
      float bd = b_dec[col];
      #pragma unroll
      for (int r = 0; r < 4; r++){
        int row = row0 + wr + mi * 16 + rq + r;
        out[(size_t)row * DIM + col] = acc[mi][ni][r] + bd;
      }
    }
  }
}

// Chunked decode — gathers a 128-col STRIPE of linear-layout wdb (stripe working
// set = 4 MB = one XCD L2, identical residency to the old chunked copy). Round-0
// loop structure (compiler-pipelined unroll-16, sse-only epilogue), actbuf
// precompute, nt streams, no fences.
__global__ __launch_bounds__(256) void decode_residual(
    const float* __restrict__ y,
    const uint2* __restrict__ actbuf,
    const unsigned short* __restrict__ Wdb,  // [NLAT][1024] bf16 (linear)
    float* __restrict__ out,
    float* __restrict__ sse){
  const int chunk = blockIdx.x & 7;          // == XCD id under round-robin dispatch
  const int tok0  = (blockIdx.x >> 3) * 16;
  const int t  = threadIdx.x;
  const int tl = t >> 4;       // token lane 0..15
  const int cl = t & 15;       // col lane (8 cols each)
  __shared__ uint2 s_ai[16][66];   // stride 66 -> conflict-free
  __shared__ float s_red[4];

  #pragma unroll
  for (int i = 0; i < 4; i++){
    int e = t + i * 256;                 // (tok = e>>6, k = e&63)
    u32x2 v = __builtin_nontemporal_load((const u32x2*)&actbuf[tok0 * KTOP + e]);
    s_ai[e >> 6][e & 63] = make_uint2(v[0], v[1]);
  }
  __syncthreads();
  const int n = tok0 + tl;
  const char* Wbase = (const char*)Wdb + chunk * 256 + cl * 16;
  float* op = out + (size_t)n * DIM + chunk * 128 + cl * 8;
  const float* yp = y + (size_t)n * DIM + chunk * 128 + cl * 8;
  f32x4 o0 = __builtin_nontemporal_load((const f32x4*)op);
  f32x4 o1 = __builtin_nontemporal_load((const f32x4*)op + 1);
  f32x4 y0 = __builtin_nontemporal_load((const f32x4*)yp);
  f32x4 y1 = __builtin_nontemporal_load((const f32x4*)yp + 1);

  float acc[8] = {};
  #pragma unroll 16
  for (int k = 0; k < KTOP; k++){
    uint2 p = s_ai[tl][k];
    const float a = __uint_as_float(p.x);
    const uint4 wv = *(const uint4*)(Wbase + p.y);   // p.y = id*2048 (row byte off)
    acc[0] += a * bflo(wv.x); acc[1] += a * bfhi(wv.x);
    acc[2] += a * bflo(wv.y); acc[3] += a * bfhi(wv.y);
    acc[4] += a * bflo(wv.z); acc[5] += a * bfhi(wv.z);
    acc[6] += a * bflo(wv.w); acc[7] += a * bfhi(wv.w);
  }
  acc[0] += o0[0]; acc[1] += o0[1]; acc[2] += o0[2]; acc[3] += o0[3];
  acc[4] += o1[0]; acc[5] += o1[1]; acc[6] += o1[2]; acc[7] += o1[3];
  f32x4 r0 = {acc[0], acc[1], acc[2], acc[3]};
  f32x4 r1 = {acc[4], acc[5], acc[6], acc[7]};
  __builtin_nontemporal_store(r0, (f32x4*)op);
  __builtin_nontemporal_store(r1, (f32x4*)op + 1);

  float e0 = y0[0]-acc[0], e1 = y0[1]-acc[1], e2 = y0[2]-acc[2], e3 = y0[3]-acc[3];
  float e4 = y1[0]-acc[4], e5 = y1[1]-acc[5], e6 = y1[2]-acc[6], e7 = y1[3]-acc[7];
  float s = e0*e0 + e1*e1 + e2*e2 + e3*e3 + e4*e4 + e5*e5 + e6*e6 + e7*e7;
  #pragma unroll
  for (int off = 32; off > 0; off >>= 1) s += __shfl_down(s, off, 64);
  if ((t & 63) == 0) s_red[t >> 6] = s;
  __syncthreads();
  if (t == 0) atomicAdd(sse, s_red[0] + s_red[1] + s_red[2] + s_red[3]);
}

// Tiny finalize: fvu = sse / (sumsq - sum(colsum^2)/N). Kernel boundary gives visibility.
__global__ __launch_bounds__(256) void fvu_kernel(
    const float* __restrict__ ws, float* __restrict__ fvu_out){
  const int t = threadIdx.x;
  float4 c = ((const float4*)(ws + 4))[t];
  float s = c.x*c.x + c.y*c.y + c.z*c.z + c.w*c.w;
  #pragma unroll
  for (int off = 32; off > 0; off >>= 1) s += __shfl_down(s, off, 64);
  __shared__ float s_red[4];
  if ((t & 63) == 0) s_red[t >> 6] = s;
  __syncthreads();
  if (t == 0){
    float ss = s_red[0] + s_red[1] + s_red[2] + s_red[3];
    float tv = ws[1] - ss / (float)N_TOK;
    fvu_out[0] = ws[0] / tv;
  }
}

extern "C" void kernel_launch(void* const* d_in, const int* in_sizes, int n_in,
                              void* d_out, int out_size, void* d_ws, size_t ws_size,
                              hipStream_t stream){
  const float* x   = (const float*)d_in[0];
  const float* y   = (const float*)d_in[1];
  const float* la  = (const float*)d_in[2];
  const int*   li  = (const int*)d_in[3];
  const float* Wd  = (const float*)d_in[4];
  const float* bd  = (const float*)d_in[5];
  const float* pe  = (const float*)d_in[6];
  const float* pes = (const float*)d_in[7];
  const float* Wsk = (const float*)d_in[8];
  float* out = (float*)d_out;

  float* accs = (float*)d_ws;  // [0]=sse [1]=sumsq [4..1028)=colsum
  unsigned short* xb  = (unsigned short*)((char*)d_ws + 8192);
  unsigned short* wb  = xb + (size_t)N_TOK * DIM;
  unsigned short* wdb = wb + (size_t)DIM * DIM;
  uint2* actbuf = (uint2*)(wdb + (size_t)NLAT * DIM);

  prep<<<2753, 256, 0, stream>>>(x, Wsk, Wd, la, li, pe, pes, xb, wb, wdb, actbuf, accs);
  skip_gemm<<<dim3(40, 16), 256, 0, stream>>>(xb, wb, bd, y, out, accs);
  decode_residual<<<(N_TOK / 16) * NCHUNK, 256, 0, stream>>>(y, actbuf, wdb, out, accs);
  fvu_kernel<<<1, 256, 0, stream>>>(accs, out + (size_t)N_TOK * DIM);
}